// Round 1
// baseline (3276.447 us; speedup 1.0000x reference)
//
#include <hip/hip_runtime.h>
#include <hip/hip_bf16.h>

#define D 128
#define BM 64
#define KC 32

// ---------------------------------------------------------------------------
// Phase 2: edge scatter. 32 threads per edge; each thread handles 4 columns.
// acc[dst] += h[src]; deg[dst] += 1 (lane 0 of each 32-group).
// ---------------------------------------------------------------------------
__global__ __launch_bounds__(256) void scatter_kernel(
    const float* __restrict__ h,
    const int* __restrict__ src,
    const int* __restrict__ dst,
    int E,
    float* __restrict__ acc,
    float* __restrict__ deg)
{
    int t = blockIdx.x * blockDim.x + threadIdx.x;
    int e = t >> 5;
    if (e >= E) return;
    int c = (t & 31) << 2;
    int s = src[e];
    int d = dst[e];
    const float4 v = *reinterpret_cast<const float4*>(&h[(size_t)s * D + c]);
    float* o = &acc[(size_t)d * D + c];
    unsafeAtomicAdd(o + 0, v.x);
    unsafeAtomicAdd(o + 1, v.y);
    unsafeAtomicAdd(o + 2, v.z);
    unsafeAtomicAdd(o + 3, v.w);
    if ((t & 31) == 0) unsafeAtomicAdd(&deg[d], 1.0f);
}

// ---------------------------------------------------------------------------
// Phase 3: fused GEMM.
// out[i][:] = A0[i] @ (W0a [+ W0b])                       (self term)
//           + (A1[i]/max(deg1[i],1)) @ W1                 (neigh rel 1)
//           + (A2[i]/max(deg2[i],1)) @ W2   (optional)    (neigh rel 2)
//           + b1 [+ b2]
// Block: BM=64 rows x 128 cols, 256 threads, per-thread 8 rows x 4 cols.
// ---------------------------------------------------------------------------
__global__ __launch_bounds__(256) void sage_gemm(
    const float* __restrict__ A0,
    const float* __restrict__ W0a, const float* __restrict__ W0b,
    const float* __restrict__ A1, const float* __restrict__ deg1, const float* __restrict__ W1,
    const float* __restrict__ A2, const float* __restrict__ deg2, const float* __restrict__ W2,
    const float* __restrict__ b1, const float* __restrict__ b2,
    float* __restrict__ out, int N)
{
    __shared__ float Ast[KC][68];   // A chunk, transposed [k][row], padded
    __shared__ float Ws[KC][D];     // W chunk [k][col]

    const int t  = threadIdx.x;
    const int row0 = blockIdx.x * BM;
    const int c0 = (t & 31) << 2;        // this thread's 4 output cols
    const int r0 = (t >> 5) << 3;        // this thread's 8 output rows (in-block)

    float4 acc[8];
#pragma unroll
    for (int i = 0; i < 8; ++i) acc[i] = make_float4(0.f, 0.f, 0.f, 0.f);

    const int nsrc = (A2 != nullptr) ? 3 : 2;
    for (int srcI = 0; srcI < nsrc; ++srcI) {
        const float* A  = (srcI == 0) ? A0 : (srcI == 1 ? A1 : A2);
        const float* W  = (srcI == 0) ? W0a : (srcI == 1 ? W1 : W2);
        const float* dg = (srcI == 0) ? nullptr : (srcI == 1 ? deg1 : deg2);

        for (int k0 = 0; k0 < D; k0 += KC) {
            __syncthreads();   // protect LDS from previous chunk's readers

            // Stage A chunk: 64 rows x 32 k, scaled by 1/deg, stored transposed.
#pragma unroll
            for (int q = 0; q < 2; ++q) {
                int slot = t * 2 + q;            // 0..511
                int r    = slot >> 3;            // 0..63
                int cc   = (slot & 7) << 2;      // 0..28
                int row  = row0 + r;
                float4 v = make_float4(0.f, 0.f, 0.f, 0.f);
                float scale = 1.0f;
                if (row < N) {
                    v = *reinterpret_cast<const float4*>(&A[(size_t)row * D + k0 + cc]);
                    if (dg) scale = 1.0f / fmaxf(dg[row], 1.0f);
                }
                Ast[cc + 0][r] = v.x * scale;
                Ast[cc + 1][r] = v.y * scale;
                Ast[cc + 2][r] = v.z * scale;
                Ast[cc + 3][r] = v.w * scale;
            }
            // Stage W chunk: 32 k x 128 cols (sum the two self-weights for srcI==0).
#pragma unroll
            for (int q = 0; q < 4; ++q) {
                int slot = t * 4 + q;            // 0..1023
                int r    = slot >> 5;            // 0..31
                int cc   = (slot & 31) << 2;     // 0..124
                float4 v = *reinterpret_cast<const float4*>(&W[(size_t)(k0 + r) * D + cc]);
                if (srcI == 0 && W0b != nullptr) {
                    float4 v2 = *reinterpret_cast<const float4*>(&W0b[(size_t)(k0 + r) * D + cc]);
                    v.x += v2.x; v.y += v2.y; v.z += v2.z; v.w += v2.w;
                }
                *reinterpret_cast<float4*>(&Ws[r][cc]) = v;
            }
            __syncthreads();

            // Compute: per k, 2 x ds_read_b128 (A) + 1 x ds_read_b128 (W) + 32 FMA.
#pragma unroll
            for (int k = 0; k < KC; ++k) {
                const float4 w    = *reinterpret_cast<const float4*>(&Ws[k][c0]);
                const float4 a_lo = *reinterpret_cast<const float4*>(&Ast[k][r0]);
                const float4 a_hi = *reinterpret_cast<const float4*>(&Ast[k][r0 + 4]);
                const float av[8] = {a_lo.x, a_lo.y, a_lo.z, a_lo.w,
                                     a_hi.x, a_hi.y, a_hi.z, a_hi.w};
#pragma unroll
                for (int i = 0; i < 8; ++i) {
                    acc[i].x = fmaf(av[i], w.x, acc[i].x);
                    acc[i].y = fmaf(av[i], w.y, acc[i].y);
                    acc[i].z = fmaf(av[i], w.z, acc[i].z);
                    acc[i].w = fmaf(av[i], w.w, acc[i].w);
                }
            }
        }
    }

    float4 bias = *reinterpret_cast<const float4*>(&b1[c0]);
    if (b2 != nullptr) {
        float4 b2v = *reinterpret_cast<const float4*>(&b2[c0]);
        bias.x += b2v.x; bias.y += b2v.y; bias.z += b2v.z; bias.w += b2v.w;
    }
#pragma unroll
    for (int i = 0; i < 8; ++i) {
        int row = row0 + r0 + i;
        if (row < N) {
            float4 o = acc[i];
            o.x += bias.x; o.y += bias.y; o.z += bias.z; o.w += bias.w;
            *reinterpret_cast<float4*>(&out[(size_t)row * D + c0]) = o;
        }
    }
}

// ---------------------------------------------------------------------------
extern "C" void kernel_launch(void* const* d_in, const int* in_sizes, int n_in,
                              void* d_out, int out_size, void* d_ws, size_t ws_size,
                              hipStream_t stream)
{
    const float* h_user    = (const float*)d_in[0];
    const float* h_item    = (const float*)d_in[1];
    const float* Wself_uu  = (const float*)d_in[2];
    const float* Wneigh_uu = (const float*)d_in[3];
    const float* b_uu      = (const float*)d_in[4];
    const float* Wself_ui  = (const float*)d_in[5];
    const float* Wneigh_ui = (const float*)d_in[6];
    const float* b_ui      = (const float*)d_in[7];
    const float* Wself_iu  = (const float*)d_in[8];
    const float* Wneigh_iu = (const float*)d_in[9];
    const float* b_iu      = (const float*)d_in[10];
    const int* e_uu_src    = (const int*)d_in[11];
    const int* e_uu_dst    = (const int*)d_in[12];
    const int* e_ui_src    = (const int*)d_in[13];
    const int* e_ui_dst    = (const int*)d_in[14];
    const int* e_iu_src    = (const int*)d_in[15];
    const int* e_iu_dst    = (const int*)d_in[16];

    const int N_USER = in_sizes[0] / D;
    const int N_ITEM = in_sizes[1] / D;
    const int E_uu = in_sizes[11];
    const int E_ui = in_sizes[13];
    const int E_iu = in_sizes[15];

    // Workspace layout (floats)
    float* ws = (float*)d_ws;
    float* accUU = ws;                                    // [N_USER * D]
    float* accIU = accUU + (size_t)N_USER * D;            // [N_USER * D]
    float* accUI = accIU + (size_t)N_USER * D;            // [N_ITEM * D]
    float* degUU = accUI + (size_t)N_ITEM * D;            // [N_USER]
    float* degIU = degUU + N_USER;                        // [N_USER]
    float* degUI = degIU + N_USER;                        // [N_ITEM]
    size_t ws_floats = (size_t)N_USER * D * 2 + (size_t)N_ITEM * D
                     + (size_t)N_USER * 2 + N_ITEM;

    hipMemsetAsync(d_ws, 0, ws_floats * sizeof(float), stream);

    // Scatter per relation (separate launches for per-relation profiling)
    {
        int thr = 256;
        int blk_uu = (E_uu * 32 + thr - 1) / thr;
        int blk_ui = (E_ui * 32 + thr - 1) / thr;
        int blk_iu = (E_iu * 32 + thr - 1) / thr;
        scatter_kernel<<<blk_uu, thr, 0, stream>>>(h_user, e_uu_src, e_uu_dst, E_uu, accUU, degUU);
        scatter_kernel<<<blk_iu, thr, 0, stream>>>(h_item, e_iu_src, e_iu_dst, E_iu, accIU, degIU);
        scatter_kernel<<<blk_ui, thr, 0, stream>>>(h_user, e_ui_src, e_ui_dst, E_ui, accUI, degUI);
    }

    float* out_user = (float*)d_out;
    float* out_item = out_user + (size_t)N_USER * D;

    int blocks_user = (N_USER + BM - 1) / BM;
    int blocks_item = (N_ITEM + BM - 1) / BM;

    // out_user = h_user @ (Wself_uu + Wself_iu) + mean_uu @ Wneigh_uu
    //          + mean_iu @ Wneigh_iu + (b_uu + b_iu)
    sage_gemm<<<blocks_user, 256, 0, stream>>>(
        h_user, Wself_uu, Wself_iu,
        accUU, degUU, Wneigh_uu,
        accIU, degIU, Wneigh_iu,
        b_uu, b_iu,
        out_user, N_USER);

    // out_item = h_item @ Wself_ui + mean_ui @ Wneigh_ui + b_ui
    sage_gemm<<<blocks_item, 256, 0, stream>>>(
        h_item, Wself_ui, nullptr,
        accUI, degUI, Wneigh_ui,
        nullptr, nullptr, nullptr,
        b_ui, nullptr,
        out_item, N_ITEM);
}

// Round 2
// 548.940 us; speedup vs baseline: 5.9687x; 5.9687x over previous
//
#include <hip/hip_runtime.h>
#include <hip/hip_bf16.h>

#define D 128
#define BM 64
#define KC 32

// ---------------------------------------------------------------------------
// CSR build step 1: histogram of destination degrees (int atomics).
// ---------------------------------------------------------------------------
__global__ __launch_bounds__(256) void hist_kernel(
    const int* __restrict__ dst, int E, int* __restrict__ deg)
{
    int e = blockIdx.x * 256 + threadIdx.x;
    if (e < E) atomicAdd(&deg[dst[e]], 1);
}

// ---------------------------------------------------------------------------
// CSR build step 2: fused exclusive scan of the 3 degree arrays.
// One block per relation; 1024 threads; sequential-chunk + Hillis-Steele.
// ---------------------------------------------------------------------------
__global__ __launch_bounds__(1024) void scan3_kernel(
    int* d0, int n0, int* d1, int n1, int* d2, int n2)
{
    int* d; int n;
    if (blockIdx.x == 0)      { d = d0; n = n0; }
    else if (blockIdx.x == 1) { d = d1; n = n1; }
    else                      { d = d2; n = n2; }

    __shared__ int part[1024];
    const int t = threadIdx.x;
    const int chunk = (n + 1023) >> 10;
    const int lo = t * chunk;
    const int hi = min(n, lo + chunk);

    int s = 0;
    for (int i = lo; i < hi; ++i) s += d[i];
    part[t] = s;
    __syncthreads();
    for (int off = 1; off < 1024; off <<= 1) {
        int v = (t >= off) ? part[t - off] : 0;
        __syncthreads();
        part[t] += v;
        __syncthreads();
    }
    int run = (t > 0) ? part[t - 1] : 0;   // exclusive prefix of this chunk
    for (int i = lo; i < hi; ++i) { int v = d[i]; d[i] = run; run += v; }
}

// ---------------------------------------------------------------------------
// CSR build step 3: scatter edge sources into sorted order.
// offs[i] is mutated from start-offset to end-offset (start = offs[i-1]).
// ---------------------------------------------------------------------------
__global__ __launch_bounds__(256) void fill_kernel(
    const int* __restrict__ src, const int* __restrict__ dst, int E,
    int* __restrict__ offs, int* __restrict__ sorted)
{
    int e = blockIdx.x * 256 + threadIdx.x;
    if (e < E) {
        int p = atomicAdd(&offs[dst[e]], 1);
        sorted[p] = src[e];
    }
}

// ---------------------------------------------------------------------------
// Gather: one wave per destination node. 64 lanes x float2 = one contiguous
// 512B source row per iteration. Neighbor ids preloaded 64-at-a-time and
// broadcast via shfl. Stores the MEAN (scale folded in) -> GEMM needs no deg.
// ---------------------------------------------------------------------------
__global__ __launch_bounds__(256) void gather_kernel(
    const float* __restrict__ h, const int* __restrict__ offs,
    const int* __restrict__ sorted, float* __restrict__ acc, int N)
{
    const int w    = (blockIdx.x * 256 + threadIdx.x) >> 6;
    const int lane = threadIdx.x & 63;
    if (w >= N) return;

    const int end   = offs[w];
    const int start = (w > 0) ? offs[w - 1] : 0;

    float2 sum = make_float2(0.f, 0.f);
    for (int base = start; base < end; base += 64) {
        const int sv = (base + lane < end) ? sorted[base + lane] : 0;
        const int m = min(64, end - base);
        for (int j = 0; j < m; ++j) {
            const int s = __shfl(sv, j);
            const float2 v = *reinterpret_cast<const float2*>(
                &h[(size_t)s * D + lane * 2]);
            sum.x += v.x; sum.y += v.y;
        }
    }
    const float scale = 1.0f / fmaxf((float)(end - start), 1.0f);
    *reinterpret_cast<float2*>(&acc[(size_t)w * D + lane * 2]) =
        make_float2(sum.x * scale, sum.y * scale);
}

// ---------------------------------------------------------------------------
// Fused GEMM:
// out[i][:] = A0[i] @ (W0a [+ W0b]) + A1[i] @ W1 [+ A2[i] @ W2] + b1 [+ b2]
// (A1/A2 are already mean-scaled by the gather.)
// Block: BM=64 rows x 128 cols, 256 threads, per-thread 8 rows x 4 cols.
// ---------------------------------------------------------------------------
__global__ __launch_bounds__(256) void sage_gemm(
    const float* __restrict__ A0,
    const float* __restrict__ W0a, const float* __restrict__ W0b,
    const float* __restrict__ A1, const float* __restrict__ W1,
    const float* __restrict__ A2, const float* __restrict__ W2,
    const float* __restrict__ b1, const float* __restrict__ b2,
    float* __restrict__ out, int N)
{
    __shared__ float Ast[KC][68];   // A chunk, transposed [k][row], padded
    __shared__ float Ws[KC][D];     // W chunk [k][col]

    const int t    = threadIdx.x;
    const int row0 = blockIdx.x * BM;
    const int c0   = (t & 31) << 2;      // this thread's 4 output cols
    const int r0   = (t >> 5) << 3;      // this thread's 8 output rows (in-block)

    float4 acc[8];
#pragma unroll
    for (int i = 0; i < 8; ++i) acc[i] = make_float4(0.f, 0.f, 0.f, 0.f);

    const int nsrc = (A2 != nullptr) ? 3 : 2;
    for (int srcI = 0; srcI < nsrc; ++srcI) {
        const float* A = (srcI == 0) ? A0 : (srcI == 1 ? A1 : A2);
        const float* W = (srcI == 0) ? W0a : (srcI == 1 ? W1 : W2);

        for (int k0 = 0; k0 < D; k0 += KC) {
            __syncthreads();

            // Stage A chunk: 64 rows x 32 k, stored transposed [k][row].
#pragma unroll
            for (int q = 0; q < 2; ++q) {
                int slot = t * 2 + q;            // 0..511
                int r    = slot >> 3;            // 0..63
                int cc   = (slot & 7) << 2;      // 0..28
                int row  = row0 + r;
                float4 v = make_float4(0.f, 0.f, 0.f, 0.f);
                if (row < N)
                    v = *reinterpret_cast<const float4*>(&A[(size_t)row * D + k0 + cc]);
                Ast[cc + 0][r] = v.x;
                Ast[cc + 1][r] = v.y;
                Ast[cc + 2][r] = v.z;
                Ast[cc + 3][r] = v.w;
            }
            // Stage W chunk: 32 k x 128 cols (sum two self-weights for srcI==0).
#pragma unroll
            for (int q = 0; q < 4; ++q) {
                int slot = t * 4 + q;            // 0..1023
                int r    = slot >> 5;            // 0..31
                int cc   = (slot & 31) << 2;     // 0..124
                float4 v = *reinterpret_cast<const float4*>(&W[(size_t)(k0 + r) * D + cc]);
                if (srcI == 0 && W0b != nullptr) {
                    float4 v2 = *reinterpret_cast<const float4*>(&W0b[(size_t)(k0 + r) * D + cc]);
                    v.x += v2.x; v.y += v2.y; v.z += v2.z; v.w += v2.w;
                }
                *reinterpret_cast<float4*>(&Ws[r][cc]) = v;
            }
            __syncthreads();

#pragma unroll
            for (int k = 0; k < KC; ++k) {
                const float4 w    = *reinterpret_cast<const float4*>(&Ws[k][c0]);
                const float4 a_lo = *reinterpret_cast<const float4*>(&Ast[k][r0]);
                const float4 a_hi = *reinterpret_cast<const float4*>(&Ast[k][r0 + 4]);
                const float av[8] = {a_lo.x, a_lo.y, a_lo.z, a_lo.w,
                                     a_hi.x, a_hi.y, a_hi.z, a_hi.w};
#pragma unroll
                for (int i = 0; i < 8; ++i) {
                    acc[i].x = fmaf(av[i], w.x, acc[i].x);
                    acc[i].y = fmaf(av[i], w.y, acc[i].y);
                    acc[i].z = fmaf(av[i], w.z, acc[i].z);
                    acc[i].w = fmaf(av[i], w.w, acc[i].w);
                }
            }
        }
    }

    float4 bias = *reinterpret_cast<const float4*>(&b1[c0]);
    if (b2 != nullptr) {
        float4 b2v = *reinterpret_cast<const float4*>(&b2[c0]);
        bias.x += b2v.x; bias.y += b2v.y; bias.z += b2v.z; bias.w += b2v.w;
    }
#pragma unroll
    for (int i = 0; i < 8; ++i) {
        int row = row0 + r0 + i;
        if (row < N) {
            float4 o = acc[i];
            o.x += bias.x; o.y += bias.y; o.z += bias.z; o.w += bias.w;
            *reinterpret_cast<float4*>(&out[(size_t)row * D + c0]) = o;
        }
    }
}

// ---------------------------------------------------------------------------
extern "C" void kernel_launch(void* const* d_in, const int* in_sizes, int n_in,
                              void* d_out, int out_size, void* d_ws, size_t ws_size,
                              hipStream_t stream)
{
    const float* h_user    = (const float*)d_in[0];
    const float* h_item    = (const float*)d_in[1];
    const float* Wself_uu  = (const float*)d_in[2];
    const float* Wneigh_uu = (const float*)d_in[3];
    const float* b_uu      = (const float*)d_in[4];
    const float* Wself_ui  = (const float*)d_in[5];
    const float* Wneigh_ui = (const float*)d_in[6];
    const float* b_ui      = (const float*)d_in[7];
    const float* Wself_iu  = (const float*)d_in[8];
    const float* Wneigh_iu = (const float*)d_in[9];
    const float* b_iu      = (const float*)d_in[10];
    const int* e_uu_src    = (const int*)d_in[11];
    const int* e_uu_dst    = (const int*)d_in[12];
    const int* e_ui_src    = (const int*)d_in[13];
    const int* e_ui_dst    = (const int*)d_in[14];
    const int* e_iu_src    = (const int*)d_in[15];
    const int* e_iu_dst    = (const int*)d_in[16];

    const int N_USER = in_sizes[0] / D;
    const int N_ITEM = in_sizes[1] / D;
    const int E_uu = in_sizes[11];
    const int E_ui = in_sizes[13];
    const int E_iu = in_sizes[15];

    // Workspace layout: [degUU, degIU, degUI | srtUU, srtIU, srtUI | accUU, accIU, accUI]
    int* degUU = (int*)d_ws;                       // N_USER
    int* degIU = degUU + N_USER;                   // N_USER
    int* degUI = degIU + N_USER;                   // N_ITEM
    int* srtUU = degUI + N_ITEM;                   // E_uu
    int* srtIU = srtUU + E_uu;                     // E_iu
    int* srtUI = srtIU + E_iu;                     // E_ui
    float* accUU = (float*)(srtUI + E_ui);         // N_USER * D
    float* accIU = accUU + (size_t)N_USER * D;     // N_USER * D
    float* accUI = accIU + (size_t)N_USER * D;     // N_ITEM * D

    // Zero only the degree counters (acc is fully overwritten by gather).
    hipMemsetAsync(d_ws, 0, (size_t)(2 * N_USER + N_ITEM) * sizeof(int), stream);

    const int thr = 256;
    // Histograms
    hist_kernel<<<(E_uu + thr - 1) / thr, thr, 0, stream>>>(e_uu_dst, E_uu, degUU);
    hist_kernel<<<(E_iu + thr - 1) / thr, thr, 0, stream>>>(e_iu_dst, E_iu, degIU);
    hist_kernel<<<(E_ui + thr - 1) / thr, thr, 0, stream>>>(e_ui_dst, E_ui, degUI);
    // Fused scan (3 blocks, one per relation)
    scan3_kernel<<<3, 1024, 0, stream>>>(degUU, N_USER, degIU, N_USER, degUI, N_ITEM);
    // Fill CSR
    fill_kernel<<<(E_uu + thr - 1) / thr, thr, 0, stream>>>(e_uu_src, e_uu_dst, E_uu, degUU, srtUU);
    fill_kernel<<<(E_iu + thr - 1) / thr, thr, 0, stream>>>(e_iu_src, e_iu_dst, E_iu, degIU, srtIU);
    fill_kernel<<<(E_ui + thr - 1) / thr, thr, 0, stream>>>(e_ui_src, e_ui_dst, E_ui, degUI, srtUI);
    // Gather means (1 wave per node, 4 waves per block)
    gather_kernel<<<(N_USER + 3) / 4, thr, 0, stream>>>(h_user, degUU, srtUU, accUU, N_USER);
    gather_kernel<<<(N_ITEM + 3) / 4, thr, 0, stream>>>(h_item, degIU, srtIU, accIU, N_USER);
    gather_kernel<<<(N_USER + 3) / 4, thr, 0, stream>>>(h_user, degUI, srtUI, accUI, N_ITEM);

    float* out_user = (float*)d_out;
    float* out_item = out_user + (size_t)N_USER * D;

    // out_user = h_user @ (Wself_uu + Wself_iu) + meanUU @ Wneigh_uu
    //          + meanIU @ Wneigh_iu + (b_uu + b_iu)
    sage_gemm<<<(N_USER + BM - 1) / BM, 256, 0, stream>>>(
        h_user, Wself_uu, Wself_iu,
        accUU, Wneigh_uu,
        accIU, Wneigh_iu,
        b_uu, b_iu,
        out_user, N_USER);

    // out_item = h_item @ Wself_ui + meanUI @ Wneigh_ui + b_ui
    sage_gemm<<<(N_ITEM + BM - 1) / BM, 256, 0, stream>>>(
        h_item, Wself_ui, nullptr,
        accUI, Wneigh_ui,
        nullptr, nullptr,
        b_ui, nullptr,
        out_item, N_ITEM);
}

// Round 3
// 342.618 us; speedup vs baseline: 9.5630x; 1.6022x over previous
//
#include <hip/hip_runtime.h>

#define D 128

typedef __attribute__((ext_vector_type(8))) short short8;
typedef __attribute__((ext_vector_type(4))) float f32x4;

__device__ inline float b2f(unsigned short u) {
    union { unsigned int u; float f; } x; x.u = ((unsigned int)u) << 16; return x.f;
}
__device__ inline unsigned short f2b(float f) {
    union { float f; unsigned int u; } x; x.f = f;
    unsigned int r = x.u + 0x7FFFu + ((x.u >> 16) & 1u);
    return (unsigned short)(r >> 16);
}

// ---------------------------------------------------------------------------
// fp32 -> bf16 feature conversion (8 elements/thread, 16B stores)
// ---------------------------------------------------------------------------
__global__ __launch_bounds__(256) void convert_h(
    const float* __restrict__ h, unsigned short* __restrict__ hb, int n)
{
    int i = (blockIdx.x * 256 + threadIdx.x) * 8;
    if (i >= n) return;
    const float4 a = *reinterpret_cast<const float4*>(h + i);
    const float4 b = *reinterpret_cast<const float4*>(h + i + 4);
    short8 o;
    o[0] = (short)f2b(a.x); o[1] = (short)f2b(a.y);
    o[2] = (short)f2b(a.z); o[3] = (short)f2b(a.w);
    o[4] = (short)f2b(b.x); o[5] = (short)f2b(b.y);
    o[6] = (short)f2b(b.z); o[7] = (short)f2b(b.w);
    *reinterpret_cast<short8*>(hb + i) = o;
}

// ---------------------------------------------------------------------------
// Pack W (row-major [k][n] fp32, optional sum of two) into MFMA fragment-
// linear bf16: frag (c,kc), lane l, elem j -> W[kc*32+(l>>4)*8+j][c*16+(l&15)]
// stored at short8 index (c*4+kc)*64 + l.
// ---------------------------------------------------------------------------
__global__ __launch_bounds__(256) void convert_w(
    const float* __restrict__ Wa, const float* __restrict__ Wb,
    short8* __restrict__ Wf)
{
    int t = blockIdx.x * 256 + threadIdx.x;      // 0..2047
    int c  = t >> 8;
    int kc = (t >> 6) & 3;
    int l  = t & 63;
    int n  = c * 16 + (l & 15);
    int k0 = kc * 32 + ((l >> 4) << 3);
    short8 o;
#pragma unroll
    for (int j = 0; j < 8; ++j) {
        float v = Wa[(k0 + j) * D + n];
        if (Wb) v += Wb[(k0 + j) * D + n];
        o[j] = (short)f2b(v);
    }
    Wf[t] = o;
}

__global__ __launch_bounds__(128) void bias_sum(
    const float* __restrict__ a, const float* __restrict__ b,
    float* __restrict__ o)
{
    int i = threadIdx.x;
    o[i] = a[i] + b[i];
}

// ---------------------------------------------------------------------------
// CSR build: histogram
// ---------------------------------------------------------------------------
__global__ __launch_bounds__(256) void hist_kernel(
    const int* __restrict__ dst, int E, int* __restrict__ deg)
{
    int e = blockIdx.x * 256 + threadIdx.x;
    if (e < E) atomicAdd(&deg[dst[e]], 1);
}

// ---------------------------------------------------------------------------
// 3-phase exclusive scan over 3 arrays. 64 blocks per relation.
// ---------------------------------------------------------------------------
__global__ __launch_bounds__(256) void scanA_kernel(
    int* d0, int n0, int* d1, int n1, int* d2, int n2, int* __restrict__ partials)
{
    int rel = blockIdx.x >> 6, blk = blockIdx.x & 63;
    int* d; int n;
    if (rel == 0)      { d = d0; n = n0; }
    else if (rel == 1) { d = d1; n = n1; }
    else               { d = d2; n = n2; }
    int chunk = (n + 63) >> 6;
    int lo = blk * chunk, hi = min(n, lo + chunk);
    int s = 0;
    for (int i = lo + threadIdx.x; i < hi; i += 256) s += d[i];
    __shared__ int red[256];
    red[threadIdx.x] = s;
    __syncthreads();
    for (int off = 128; off > 0; off >>= 1) {
        if (threadIdx.x < off) red[threadIdx.x] += red[threadIdx.x + off];
        __syncthreads();
    }
    if (threadIdx.x == 0) partials[rel * 64 + blk] = red[0];
}

__global__ __launch_bounds__(192) void scanB_kernel(int* __restrict__ partials)
{
    // exclusive scan of each 64-entry segment (Hillis-Steele in LDS)
    __shared__ int s[192];
    int t = threadIdx.x, i = t & 63;
    int v = partials[t];
    s[t] = v;
    __syncthreads();
    for (int off = 1; off < 64; off <<= 1) {
        int x = (i >= off) ? s[t - off] : 0;
        __syncthreads();
        s[t] += x;
        __syncthreads();
    }
    partials[t] = s[t] - v;   // exclusive
}

__global__ __launch_bounds__(256) void scanC_kernel(
    int* d0, int n0, int* d1, int n1, int* d2, int n2,
    const int* __restrict__ partials)
{
    int rel = blockIdx.x >> 6, blk = blockIdx.x & 63;
    int* d; int n;
    if (rel == 0)      { d = d0; n = n0; }
    else if (rel == 1) { d = d1; n = n1; }
    else               { d = d2; n = n2; }
    int chunk = (n + 63) >> 6;
    int lo = blk * chunk, hi = min(n, lo + chunk);
    int sub = (chunk + 255) >> 8;
    int mylo = lo + threadIdx.x * sub;
    int myhi = min(hi, mylo + sub);
    int msum = 0;
    for (int i = mylo; i < myhi; ++i) msum += d[i];
    __shared__ int s[256];
    int t = threadIdx.x;
    s[t] = msum;
    __syncthreads();
    for (int off = 1; off < 256; off <<= 1) {
        int x = (t >= off) ? s[t - off] : 0;
        __syncthreads();
        s[t] += x;
        __syncthreads();
    }
    int run = partials[rel * 64 + blk] + s[t] - msum;
    for (int i = mylo; i < myhi; ++i) { int v = d[i]; d[i] = run; run += v; }
}

// ---------------------------------------------------------------------------
// CSR fill: offs[i] mutates start -> end offset.
// ---------------------------------------------------------------------------
__global__ __launch_bounds__(256) void fill_kernel(
    const int* __restrict__ src, const int* __restrict__ dst, int E,
    int* __restrict__ offs, int* __restrict__ sorted)
{
    int e = blockIdx.x * 256 + threadIdx.x;
    if (e < E) {
        int p = atomicAdd(&offs[dst[e]], 1);
        sorted[p] = src[e];
    }
}

// ---------------------------------------------------------------------------
// Gather mean (bf16 in / bf16 out). One wave per node; 4 neighbors per
// iteration: slot = l>>4 picks neighbor, 16 lanes x 16B cover the 256B row.
// ---------------------------------------------------------------------------
__global__ __launch_bounds__(256) void gather_kernel(
    const unsigned short* __restrict__ hb, const int* __restrict__ offs,
    const int* __restrict__ sorted, unsigned short* __restrict__ acc, int N)
{
    const int w    = (blockIdx.x * 256 + threadIdx.x) >> 6;
    const int lane = threadIdx.x & 63;
    if (w >= N) return;

    const int end   = offs[w];
    const int start = (w > 0) ? offs[w - 1] : 0;
    const int part  = lane & 15;    // 16B column chunk
    const int slot  = lane >> 4;    // neighbor slot 0..3

    float s[8];
#pragma unroll
    for (int j = 0; j < 8; ++j) s[j] = 0.f;

    for (int base = start; base < end; base += 4) {
        int idx = base + slot;
        if (idx < end) {
            int sv = sorted[idx];
            short8 v = *reinterpret_cast<const short8*>(
                hb + (size_t)sv * D + part * 8);
#pragma unroll
            for (int j = 0; j < 8; ++j) s[j] += b2f((unsigned short)v[j]);
        }
    }
#pragma unroll
    for (int j = 0; j < 8; ++j) {
        s[j] += __shfl_xor(s[j], 16);
        s[j] += __shfl_xor(s[j], 32);
    }
    if (slot == 0) {
        const float scale = 1.0f / fmaxf((float)(end - start), 1.0f);
        short8 o;
#pragma unroll
        for (int j = 0; j < 8; ++j) o[j] = (short)f2b(s[j] * scale);
        *reinterpret_cast<short8*>(acc + (size_t)w * D + part * 8) = o;
    }
}

// ---------------------------------------------------------------------------
// MFMA GEMM: out[N,128] = A0@W0 + A1@W1 [+ A2@W2] + bias. A* are bf16 [N,128];
// W* are fragment-linear bf16 (see convert_w). 8 waves, each 16 rows x 128.
// ---------------------------------------------------------------------------
__global__ __launch_bounds__(512) void sage_gemm_mfma(
    const unsigned short* __restrict__ A0,
    const unsigned short* __restrict__ A1,
    const unsigned short* __restrict__ A2,
    const short8* __restrict__ Wf0, const short8* __restrict__ Wf1,
    const short8* __restrict__ Wf2,
    const float* __restrict__ bias, float* __restrict__ out, int N)
{
    __shared__ short8 lds[2048];     // 32 KB: one fragment-linear W
    const int t = threadIdx.x;
    const int w = t >> 6, l = t & 63;
    const int row0 = blockIdx.x * 128 + w * 16;
    const int arow = row0 + (l & 15);

    f32x4 acc[8];
#pragma unroll
    for (int c = 0; c < 8; ++c) acc[c] = (f32x4){0.f, 0.f, 0.f, 0.f};

    const unsigned short* As[3] = {A0, A1, A2};
    const short8* Wfs[3] = {Wf0, Wf1, Wf2};
    const int nsrc = (A2 != nullptr) ? 3 : 2;

    for (int sI = 0; sI < nsrc; ++sI) {
        __syncthreads();
        const short8* Wg = Wfs[sI];
#pragma unroll
        for (int i = 0; i < 4; ++i) lds[t + i * 512] = Wg[t + i * 512];
        __syncthreads();

        const unsigned short* A = As[sI];
        short8 af[4];
        if (arow < N) {
            const unsigned short* base = A + (size_t)arow * D + ((l >> 4) << 3);
#pragma unroll
            for (int kc = 0; kc < 4; ++kc)
                af[kc] = *reinterpret_cast<const short8*>(base + kc * 32);
        } else {
            short8 z = {0, 0, 0, 0, 0, 0, 0, 0};
#pragma unroll
            for (int kc = 0; kc < 4; ++kc) af[kc] = z;
        }
#pragma unroll
        for (int kc = 0; kc < 4; ++kc)
#pragma unroll
            for (int c = 0; c < 8; ++c)
                acc[c] = __builtin_amdgcn_mfma_f32_16x16x32_bf16(
                    af[kc], lds[(c * 4 + kc) * 64 + l], acc[c], 0, 0, 0);
    }

    const int col = l & 15;
#pragma unroll
    for (int c = 0; c < 8; ++c) {
        float bv = bias[c * 16 + col];
#pragma unroll
        for (int r = 0; r < 4; ++r) {
            int row = row0 + ((l >> 4) << 2) + r;
            if (row < N)
                out[(size_t)row * D + c * 16 + col] = acc[c][r] + bv;
        }
    }
}

// ---------------------------------------------------------------------------
extern "C" void kernel_launch(void* const* d_in, const int* in_sizes, int n_in,
                              void* d_out, int out_size, void* d_ws, size_t ws_size,
                              hipStream_t stream)
{
    const float* h_user    = (const float*)d_in[0];
    const float* h_item    = (const float*)d_in[1];
    const float* Wself_uu  = (const float*)d_in[2];
    const float* Wneigh_uu = (const float*)d_in[3];
    const float* b_uu      = (const float*)d_in[4];
    const float* Wself_ui  = (const float*)d_in[5];
    const float* Wneigh_ui = (const float*)d_in[6];
    const float* b_ui      = (const float*)d_in[7];
    const float* Wself_iu  = (const float*)d_in[8];
    const float* Wneigh_iu = (const float*)d_in[9];
    const float* b_iu      = (const float*)d_in[10];
    const int* e_uu_src    = (const int*)d_in[11];
    const int* e_uu_dst    = (const int*)d_in[12];
    const int* e_ui_src    = (const int*)d_in[13];
    const int* e_ui_dst    = (const int*)d_in[14];
    const int* e_iu_src    = (const int*)d_in[15];
    const int* e_iu_dst    = (const int*)d_in[16];

    const int NU = in_sizes[0] / D;
    const int NI = in_sizes[1] / D;
    const int E_uu = in_sizes[11];
    const int E_ui = in_sizes[13];
    const int E_iu = in_sizes[15];

    // ---- workspace carve-up (all chunks 16B-aligned) ----
    char* p = (char*)d_ws;
    unsigned short* hbU  = (unsigned short*)p; p += (size_t)NU * D * 2;
    unsigned short* hbI  = (unsigned short*)p; p += (size_t)NI * D * 2;
    unsigned short* accUU = (unsigned short*)p; p += (size_t)NU * D * 2;
    unsigned short* accIU = (unsigned short*)p; p += (size_t)NU * D * 2;
    unsigned short* accUI = (unsigned short*)p; p += (size_t)NI * D * 2;
    short8* WfU0 = (short8*)p; p += 32768;
    short8* WfU1 = (short8*)p; p += 32768;
    short8* WfU2 = (short8*)p; p += 32768;
    short8* WfI0 = (short8*)p; p += 32768;
    short8* WfI1 = (short8*)p; p += 32768;
    float* bsum  = (float*)p;  p += 512;
    int* degUU = (int*)p; p += (size_t)NU * 4;
    int* degIU = (int*)p; p += (size_t)NU * 4;
    int* degUI = (int*)p; p += (size_t)NI * 4;
    int* partials = (int*)p; p += 192 * 4;
    int* srtUU = (int*)p; p += (size_t)E_uu * 4;
    int* srtIU = (int*)p; p += (size_t)E_iu * 4;
    int* srtUI = (int*)p; p += (size_t)E_ui * 4;

    // zero the degree counters only
    hipMemsetAsync(degUU, 0, (size_t)(2 * NU + NI) * sizeof(int), stream);

    const int thr = 256;
    // bf16 conversions
    convert_h<<<(NU * D / 8 + thr - 1) / thr, thr, 0, stream>>>(h_user, hbU, NU * D);
    convert_h<<<(NI * D / 8 + thr - 1) / thr, thr, 0, stream>>>(h_item, hbI, NI * D);
    convert_w<<<8, thr, 0, stream>>>(Wself_uu, Wself_iu, WfU0);
    convert_w<<<8, thr, 0, stream>>>(Wneigh_uu, nullptr, WfU1);
    convert_w<<<8, thr, 0, stream>>>(Wneigh_iu, nullptr, WfU2);
    convert_w<<<8, thr, 0, stream>>>(Wself_ui, nullptr, WfI0);
    convert_w<<<8, thr, 0, stream>>>(Wneigh_ui, nullptr, WfI1);
    bias_sum<<<1, 128, 0, stream>>>(b_uu, b_iu, bsum);

    // CSR build
    hist_kernel<<<(E_uu + thr - 1) / thr, thr, 0, stream>>>(e_uu_dst, E_uu, degUU);
    hist_kernel<<<(E_iu + thr - 1) / thr, thr, 0, stream>>>(e_iu_dst, E_iu, degIU);
    hist_kernel<<<(E_ui + thr - 1) / thr, thr, 0, stream>>>(e_ui_dst, E_ui, degUI);
    scanA_kernel<<<192, thr, 0, stream>>>(degUU, NU, degIU, NU, degUI, NI, partials);
    scanB_kernel<<<1, 192, 0, stream>>>(partials);
    scanC_kernel<<<192, thr, 0, stream>>>(degUU, NU, degIU, NU, degUI, NI, partials);
    fill_kernel<<<(E_uu + thr - 1) / thr, thr, 0, stream>>>(e_uu_src, e_uu_dst, E_uu, degUU, srtUU);
    fill_kernel<<<(E_iu + thr - 1) / thr, thr, 0, stream>>>(e_iu_src, e_iu_dst, E_iu, degIU, srtIU);
    fill_kernel<<<(E_ui + thr - 1) / thr, thr, 0, stream>>>(e_ui_src, e_ui_dst, E_ui, degUI, srtUI);

    // Gather means (1 wave/node)
    gather_kernel<<<(NU + 3) / 4, thr, 0, stream>>>(hbU, degUU, srtUU, accUU, NU);
    gather_kernel<<<(NI + 3) / 4, thr, 0, stream>>>(hbI, degIU, srtIU, accIU, NU);
    gather_kernel<<<(NU + 3) / 4, thr, 0, stream>>>(hbU, degUI, srtUI, accUI, NI);

    float* out_user = (float*)d_out;
    float* out_item = out_user + (size_t)NU * D;

    sage_gemm_mfma<<<(NU + 127) / 128, 512, 0, stream>>>(
        hbU, accUU, accIU, WfU0, WfU1, WfU2, bsum, out_user, NU);
    sage_gemm_mfma<<<(NI + 127) / 128, 512, 0, stream>>>(
        hbI, accUI, nullptr, WfI0, WfI1, nullptr, b_ui, out_item, NI);
}

// Round 4
// 307.087 us; speedup vs baseline: 10.6694x; 1.1157x over previous
//
#include <hip/hip_runtime.h>

#define D 128

typedef __attribute__((ext_vector_type(8))) short short8;
typedef __attribute__((ext_vector_type(4))) float f32x4;

__device__ inline float b2f(unsigned short u) {
    union { unsigned int u; float f; } x; x.u = ((unsigned int)u) << 16; return x.f;
}
__device__ inline unsigned short f2b(float f) {
    union { float f; unsigned int u; } x; x.f = f;
    unsigned int r = x.u + 0x7FFFu + ((x.u >> 16) & 1u);
    return (unsigned short)(r >> 16);
}

// ---------------------------------------------------------------------------
// phase1 (fused): h fp32->bf16 conversion | W fragment packing | bias sum |
// degree histograms. Independent work, dispatched by block range.
// ---------------------------------------------------------------------------
__global__ __launch_bounds__(256) void phase1(
    const float* __restrict__ hU, const float* __restrict__ hI,
    int nU8, int nI8,
    unsigned short* __restrict__ hbU, unsigned short* __restrict__ hbI,
    const float* __restrict__ Wself_uu, const float* __restrict__ Wself_iu,
    const float* __restrict__ Wneigh_uu, const float* __restrict__ Wneigh_iu,
    const float* __restrict__ Wself_ui, const float* __restrict__ Wneigh_ui,
    short8* __restrict__ WfU0, short8* __restrict__ WfU1, short8* __restrict__ WfU2,
    short8* __restrict__ WfI0, short8* __restrict__ WfI1,
    const float* __restrict__ b_uu, const float* __restrict__ b_iu,
    float* __restrict__ bsum,
    const int* __restrict__ d_uu, int E_uu,
    const int* __restrict__ d_iu, int E_iu,
    const int* __restrict__ d_ui, int E_ui,
    int* __restrict__ degUU, int* __restrict__ degIU, int* __restrict__ degUI,
    int nConvH)
{
    const int b = blockIdx.x;
    const int t = threadIdx.x;

    if (b < nConvH) {
        // ---- h conversion: 8 floats per thread ----
        int g = b * 256 + t;
        const float* src; unsigned short* dst;
        if (g < nU8) { src = hU + (size_t)g * 8; dst = hbU + (size_t)g * 8; }
        else {
            g -= nU8;
            if (g >= nI8) return;
            src = hI + (size_t)g * 8; dst = hbI + (size_t)g * 8;
        }
        const float4 a = *reinterpret_cast<const float4*>(src);
        const float4 c = *reinterpret_cast<const float4*>(src + 4);
        short8 o;
        o[0] = (short)f2b(a.x); o[1] = (short)f2b(a.y);
        o[2] = (short)f2b(a.z); o[3] = (short)f2b(a.w);
        o[4] = (short)f2b(c.x); o[5] = (short)f2b(c.y);
        o[6] = (short)f2b(c.z); o[7] = (short)f2b(c.w);
        *reinterpret_cast<short8*>(dst) = o;
        return;
    }
    const int wb = b - nConvH;
    if (wb < 40) {
        // ---- W fragment packing: weight wb>>3, slot within ----
        const float* Wa; const float* Wb = nullptr; short8* Wf;
        switch (wb >> 3) {
            case 0: Wa = Wself_uu; Wb = Wself_iu; Wf = WfU0; break;
            case 1: Wa = Wneigh_uu; Wf = WfU1; break;
            case 2: Wa = Wneigh_iu; Wf = WfU2; break;
            case 3: Wa = Wself_ui;  Wf = WfI0; break;
            default: Wa = Wneigh_ui; Wf = WfI1; break;
        }
        int t2 = (wb & 7) * 256 + t;            // 0..2047
        int c  = t2 >> 8;
        int kc = (t2 >> 6) & 3;
        int l  = t2 & 63;
        int n  = c * 16 + (l & 15);
        int k0 = kc * 32 + ((l >> 4) << 3);
        short8 o;
#pragma unroll
        for (int j = 0; j < 8; ++j) {
            float v = Wa[(k0 + j) * D + n];
            if (Wb) v += Wb[(k0 + j) * D + n];
            o[j] = (short)f2b(v);
        }
        Wf[t2] = o;
        return;
    }
    if (wb == 40) {
        if (t < D) bsum[t] = b_uu[t] + b_iu[t];
        return;
    }
    // ---- histogram: 4 edges per thread over concatenated edge lists ----
    const int ET = E_uu + E_iu + E_ui;
    int e0 = (wb - 41) * 1024 + t * 4;
#pragma unroll
    for (int j = 0; j < 4; ++j) {
        int e = e0 + j;
        if (e >= ET) return;
        if (e < E_uu)               atomicAdd(&degUU[d_uu[e]], 1);
        else if (e < E_uu + E_iu)   atomicAdd(&degIU[d_iu[e - E_uu]], 1);
        else                        atomicAdd(&degUI[d_ui[e - E_uu - E_iu]], 1);
    }
}

// ---------------------------------------------------------------------------
// 3-phase exclusive scan over the 3 degree arrays (64 blocks per relation).
// ---------------------------------------------------------------------------
__global__ __launch_bounds__(256) void scanA_kernel(
    int* d0, int n0, int* d1, int n1, int* d2, int n2, int* __restrict__ partials)
{
    int rel = blockIdx.x >> 6, blk = blockIdx.x & 63;
    int* d; int n;
    if (rel == 0)      { d = d0; n = n0; }
    else if (rel == 1) { d = d1; n = n1; }
    else               { d = d2; n = n2; }
    int chunk = (n + 63) >> 6;
    int lo = blk * chunk, hi = min(n, lo + chunk);
    int s = 0;
    for (int i = lo + threadIdx.x; i < hi; i += 256) s += d[i];
    __shared__ int red[256];
    red[threadIdx.x] = s;
    __syncthreads();
    for (int off = 128; off > 0; off >>= 1) {
        if (threadIdx.x < off) red[threadIdx.x] += red[threadIdx.x + off];
        __syncthreads();
    }
    if (threadIdx.x == 0) partials[rel * 64 + blk] = red[0];
}

__global__ __launch_bounds__(192) void scanB_kernel(int* __restrict__ partials)
{
    __shared__ int s[192];
    int t = threadIdx.x, i = t & 63;
    int v = partials[t];
    s[t] = v;
    __syncthreads();
    for (int off = 1; off < 64; off <<= 1) {
        int x = (i >= off) ? s[t - off] : 0;
        __syncthreads();
        s[t] += x;
        __syncthreads();
    }
    partials[t] = s[t] - v;   // exclusive
}

__global__ __launch_bounds__(256) void scanC_kernel(
    int* d0, int n0, int* d1, int n1, int* d2, int n2,
    const int* __restrict__ partials)
{
    int rel = blockIdx.x >> 6, blk = blockIdx.x & 63;
    int* d; int n;
    if (rel == 0)      { d = d0; n = n0; }
    else if (rel == 1) { d = d1; n = n1; }
    else               { d = d2; n = n2; }
    int chunk = (n + 63) >> 6;
    int lo = blk * chunk, hi = min(n, lo + chunk);
    int sub = (chunk + 255) >> 8;
    int mylo = lo + threadIdx.x * sub;
    int myhi = min(hi, mylo + sub);
    int msum = 0;
    for (int i = mylo; i < myhi; ++i) msum += d[i];
    __shared__ int s[256];
    int t = threadIdx.x;
    s[t] = msum;
    __syncthreads();
    for (int off = 1; off < 256; off <<= 1) {
        int x = (t >= off) ? s[t - off] : 0;
        __syncthreads();
        s[t] += x;
        __syncthreads();
    }
    int run = partials[rel * 64 + blk] + s[t] - msum;
    for (int i = mylo; i < myhi; ++i) { int v = d[i]; d[i] = run; run += v; }
}

// ---------------------------------------------------------------------------
// fill (fused): scatter edge sources into CSR order; offs mutates start->end.
// ---------------------------------------------------------------------------
__global__ __launch_bounds__(256) void fill_all(
    const int* __restrict__ s_uu, const int* __restrict__ d_uu, int E_uu,
    const int* __restrict__ s_iu, const int* __restrict__ d_iu, int E_iu,
    const int* __restrict__ s_ui, const int* __restrict__ d_ui, int E_ui,
    int* __restrict__ degUU, int* __restrict__ degIU, int* __restrict__ degUI,
    int* __restrict__ srtUU, int* __restrict__ srtIU, int* __restrict__ srtUI)
{
    const int ET = E_uu + E_iu + E_ui;
    int e0 = blockIdx.x * 1024 + threadIdx.x * 4;
#pragma unroll
    for (int j = 0; j < 4; ++j) {
        int e = e0 + j;
        if (e >= ET) return;
        const int* src; const int* dst; int* offs; int* sorted;
        if (e < E_uu)             { src = s_uu; dst = d_uu; offs = degUU; sorted = srtUU; }
        else if (e < E_uu + E_iu) { e -= E_uu; src = s_iu; dst = d_iu; offs = degIU; sorted = srtIU; }
        else                      { e -= E_uu + E_iu; src = s_ui; dst = d_ui; offs = degUI; sorted = srtUI; }
        int p = atomicAdd(&offs[dst[e]], 1);
        sorted[p] = src[e];
        e0 = e0;   // keep e0 in terms of global index
        // restore nothing: e was shadowed per-iteration via local copy
    }
}

// ---------------------------------------------------------------------------
// gather (fused): one wave per destination node across all 3 relations.
// 4 neighbors in flight (slot = lane>>4), 16 lanes x 16B per 256B row.
// Stores the MEAN in bf16.
// ---------------------------------------------------------------------------
__global__ __launch_bounds__(256) void gather_all(
    const unsigned short* __restrict__ hbU, const unsigned short* __restrict__ hbI,
    const int* __restrict__ degUU, const int* __restrict__ srtUU,
    const int* __restrict__ degIU, const int* __restrict__ srtIU,
    const int* __restrict__ degUI, const int* __restrict__ srtUI,
    unsigned short* __restrict__ accUU, unsigned short* __restrict__ accIU,
    unsigned short* __restrict__ accUI,
    int NU, int NI)
{
    int w = (blockIdx.x * 256 + threadIdx.x) >> 6;
    const int lane = threadIdx.x & 63;

    const unsigned short* hb; const int* offs; const int* sorted;
    unsigned short* acc;
    if (w < NU)            { hb = hbU; offs = degUU; sorted = srtUU; acc = accUU; }
    else if (w < 2 * NU)   { w -= NU; hb = hbI; offs = degIU; sorted = srtIU; acc = accIU; }
    else                   { w -= 2 * NU; if (w >= NI) return;
                             hb = hbU; offs = degUI; sorted = srtUI; acc = accUI; }

    const int end   = offs[w];
    const int start = (w > 0) ? offs[w - 1] : 0;
    const int part  = lane & 15;
    const int slot  = lane >> 4;

    float s[8];
#pragma unroll
    for (int j = 0; j < 8; ++j) s[j] = 0.f;

    for (int base = start; base < end; base += 4) {
        int idx = base + slot;
        if (idx < end) {
            int sv = sorted[idx];
            short8 v = *reinterpret_cast<const short8*>(
                hb + (size_t)sv * D + part * 8);
#pragma unroll
            for (int j = 0; j < 8; ++j) s[j] += b2f((unsigned short)v[j]);
        }
    }
#pragma unroll
    for (int j = 0; j < 8; ++j) {
        s[j] += __shfl_xor(s[j], 16);
        s[j] += __shfl_xor(s[j], 32);
    }
    if (slot == 0) {
        const float scale = 1.0f / fmaxf((float)(end - start), 1.0f);
        short8 o;
#pragma unroll
        for (int j = 0; j < 8; ++j) o[j] = (short)f2b(s[j] * scale);
        *reinterpret_cast<short8*>(acc + (size_t)w * D + part * 8) = o;
    }
}

// ---------------------------------------------------------------------------
// GEMM (fused): both output types in one launch, branch on block range.
// out[N,128] = A0@W0 + A1@W1 [+ A2@W2] + bias; W* fragment-linear bf16.
// 8 waves/block, each computes 16 rows x 128 cols.
// ---------------------------------------------------------------------------
__global__ __launch_bounds__(512) void gemm_all(
    const unsigned short* __restrict__ hbU,
    const unsigned short* __restrict__ accUU, const unsigned short* __restrict__ accIU,
    const short8* __restrict__ WfU0, const short8* __restrict__ WfU1,
    const short8* __restrict__ WfU2, const float* __restrict__ bsum,
    const unsigned short* __restrict__ hbI, const unsigned short* __restrict__ accUI,
    const short8* __restrict__ WfI0, const short8* __restrict__ WfI1,
    const float* __restrict__ b_ui,
    float* __restrict__ outU, float* __restrict__ outI,
    int NU, int NI, int nBlkU)
{
    __shared__ short8 lds[2048];     // 32 KB: one fragment-linear W
    const int t = threadIdx.x;
    const int w = t >> 6, l = t & 63;

    const unsigned short *A0, *A1, *A2;
    const short8 *W0, *W1, *W2;
    const float* bias; float* out; int N; int blk;
    if (blockIdx.x < nBlkU) {
        blk = blockIdx.x;
        A0 = hbU; A1 = accUU; A2 = accIU;
        W0 = WfU0; W1 = WfU1; W2 = WfU2;
        bias = bsum; out = outU; N = NU;
    } else {
        blk = blockIdx.x - nBlkU;
        A0 = hbI; A1 = accUI; A2 = nullptr;
        W0 = WfI0; W1 = WfI1; W2 = nullptr;
        bias = b_ui; out = outI; N = NI;
    }

    const int row0 = blk * 128 + w * 16;
    const int arow = row0 + (l & 15);

    f32x4 acc[8];
#pragma unroll
    for (int c = 0; c < 8; ++c) acc[c] = (f32x4){0.f, 0.f, 0.f, 0.f};

    const unsigned short* As[3] = {A0, A1, A2};
    const short8* Wfs[3] = {W0, W1, W2};
    const int nsrc = (A2 != nullptr) ? 3 : 2;

    for (int sI = 0; sI < nsrc; ++sI) {
        __syncthreads();
        const short8* Wg = Wfs[sI];
#pragma unroll
        for (int i = 0; i < 4; ++i) lds[t + i * 512] = Wg[t + i * 512];
        __syncthreads();

        const unsigned short* A = As[sI];
        short8 af[4];
        if (arow < N) {
            const unsigned short* base = A + (size_t)arow * D + ((l >> 4) << 3);
#pragma unroll
            for (int kc = 0; kc < 4; ++kc)
                af[kc] = *reinterpret_cast<const short8*>(base + kc * 32);
        } else {
            short8 z = {0, 0, 0, 0, 0, 0, 0, 0};
#pragma unroll
            for (int kc = 0; kc < 4; ++kc) af[kc] = z;
        }
#pragma unroll
        for (int kc = 0; kc < 4; ++kc)
#pragma unroll
            for (int c = 0; c < 8; ++c)
                acc[c] = __builtin_amdgcn_mfma_f32_16x16x32_bf16(
                    af[kc], lds[(c * 4 + kc) * 64 + l], acc[c], 0, 0, 0);
    }

    const int col = l & 15;
#pragma unroll
    for (int c = 0; c < 8; ++c) {
        float bv = bias[c * 16 + col];
#pragma unroll
        for (int r = 0; r < 4; ++r) {
            int row = row0 + ((l >> 4) << 2) + r;
            if (row < N)
                out[(size_t)row * D + c * 16 + col] = acc[c][r] + bv;
        }
    }
}

// ---------------------------------------------------------------------------
extern "C" void kernel_launch(void* const* d_in, const int* in_sizes, int n_in,
                              void* d_out, int out_size, void* d_ws, size_t ws_size,
                              hipStream_t stream)
{
    const float* h_user    = (const float*)d_in[0];
    const float* h_item    = (const float*)d_in[1];
    const float* Wself_uu  = (const float*)d_in[2];
    const float* Wneigh_uu = (const float*)d_in[3];
    const float* b_uu      = (const float*)d_in[4];
    const float* Wself_ui  = (const float*)d_in[5];
    const float* Wneigh_ui = (const float*)d_in[6];
    const float* b_ui      = (const float*)d_in[7];
    const float* Wself_iu  = (const float*)d_in[8];
    const float* Wneigh_iu = (const float*)d_in[9];
    const float* b_iu      = (const float*)d_in[10];
    const int* e_uu_src    = (const int*)d_in[11];
    const int* e_uu_dst    = (const int*)d_in[12];
    const int* e_ui_src    = (const int*)d_in[13];
    const int* e_ui_dst    = (const int*)d_in[14];
    const int* e_iu_src    = (const int*)d_in[15];
    const int* e_iu_dst    = (const int*)d_in[16];

    const int NU = in_sizes[0] / D;
    const int NI = in_sizes[1] / D;
    const int E_uu = in_sizes[11];
    const int E_ui = in_sizes[13];
    const int E_iu = in_sizes[15];

    // ---- workspace carve-up (16B-aligned chunks) ----
    char* p = (char*)d_ws;
    unsigned short* hbU   = (unsigned short*)p; p += (size_t)NU * D * 2;
    unsigned short* hbI   = (unsigned short*)p; p += (size_t)NI * D * 2;
    unsigned short* accUU = (unsigned short*)p; p += (size_t)NU * D * 2;
    unsigned short* accIU = (unsigned short*)p; p += (size_t)NU * D * 2;
    unsigned short* accUI = (unsigned short*)p; p += (size_t)NI * D * 2;
    short8* WfU0 = (short8*)p; p += 32768;
    short8* WfU1 = (short8*)p; p += 32768;
    short8* WfU2 = (short8*)p; p += 32768;
    short8* WfI0 = (short8*)p; p += 32768;
    short8* WfI1 = (short8*)p; p += 32768;
    float* bsum  = (float*)p;  p += 512;
    int* degUU = (int*)p; p += (size_t)NU * 4;
    int* degIU = (int*)p; p += (size_t)NU * 4;
    int* degUI = (int*)p; p += (size_t)NI * 4;
    int* partials = (int*)p; p += 192 * 4;
    int* srtUU = (int*)p; p += (size_t)E_uu * 4;
    int* srtIU = (int*)p; p += (size_t)E_iu * 4;
    int* srtUI = (int*)p; p += (size_t)E_ui * 4;

    // zero the degree counters only
    hipMemsetAsync(degUU, 0, (size_t)(2 * NU + NI) * sizeof(int), stream);

    const int ET = E_uu + E_iu + E_ui;
    const int nU8 = NU * D / 8, nI8 = NI * D / 8;
    const int nConvH = (nU8 + nI8 + 255) / 256;
    const int nHist  = (ET + 1023) / 1024;

    phase1<<<nConvH + 41 + nHist, 256, 0, stream>>>(
        h_user, h_item, nU8, nI8, hbU, hbI,
        Wself_uu, Wself_iu, Wneigh_uu, Wneigh_iu, Wself_ui, Wneigh_ui,
        WfU0, WfU1, WfU2, WfI0, WfI1,
        b_uu, b_iu, bsum,
        e_uu_dst, E_uu, e_iu_dst, E_iu, e_ui_dst, E_ui,
        degUU, degIU, degUI, nConvH);

    scanA_kernel<<<192, 256, 0, stream>>>(degUU, NU, degIU, NU, degUI, NI, partials);
    scanB_kernel<<<1, 192, 0, stream>>>(partials);
    scanC_kernel<<<192, 256, 0, stream>>>(degUU, NU, degIU, NU, degUI, NI, partials);

    fill_all<<<(ET + 1023) / 1024, 256, 0, stream>>>(
        e_uu_src, e_uu_dst, E_uu,
        e_iu_src, e_iu_dst, E_iu,
        e_ui_src, e_ui_dst, E_ui,
        degUU, degIU, degUI, srtUU, srtIU, srtUI);

    gather_all<<<(2 * NU + NI + 3) / 4, 256, 0, stream>>>(
        hbU, hbI, degUU, srtUU, degIU, srtIU, degUI, srtUI,
        accUU, accIU, accUI, NU, NI);

    float* out_user = (float*)d_out;
    float* out_item = out_user + (size_t)NU * D;
    const int nBlkU = (NU + 127) / 128, nBlkI = (NI + 127) / 128;

    gemm_all<<<nBlkU + nBlkI, 512, 0, stream>>>(
        hbU, accUU, accIU, WfU0, WfU1, WfU2, bsum,
        hbI, accUI, WfI0, WfI1, b_ui,
        out_user, out_item, NU, NI, nBlkU);
}